// Round 6
// baseline (685.758 us; speedup 1.0000x reference)
//
#include <hip/hip_runtime.h>
#include <hip/hip_bf16.h>

using bf16_t = __hip_bfloat16;
using bf16x8 = __attribute__((ext_vector_type(8))) __bf16;
using f32x4  = __attribute__((ext_vector_type(4))) float;

#define MFMA(a, b, c) __builtin_amdgcn_mfma_f32_16x16x32_bf16((a), (b), (c), 0, 0, 0)

#define GLOAD_LDS(g, l) __builtin_amdgcn_global_load_lds(                      \
    (const __attribute__((address_space(1))) void*)(g),                        \
    (__attribute__((address_space(3))) void*)(l), 16, 0, 0)

static __device__ __forceinline__ unsigned pk_bf16(float lo, float hi) {
  unsigned r;
  asm volatile("v_cvt_pk_bf16_f32 %0, %1, %2" : "=v"(r) : "v"(lo), "v"(hi));
  return r;
}

// B=8, C=256, N=4096(=64x64), 16 groups of 16 channels. f32 I/O, bf16 internal.

// -------- convert 4 weight matrices (256x256 f32) to bf16 ----------------
__global__ __launch_bounds__(256) void cvtw_kernel(
    const float* __restrict__ w0, const float* __restrict__ w1,
    const float* __restrict__ w2, const float* __restrict__ w3,
    bf16_t* __restrict__ dst)
{
  const float* s;
  switch (blockIdx.y) {
    case 0: s = w0; break;
    case 1: s = w1; break;
    case 2: s = w2; break;
    default: s = w3; break;
  }
  bf16_t* d = dst + (long)blockIdx.y * 65536;
  const int i = (blockIdx.x * 256 + threadIdx.x) * 4;
  float4 v = *(const float4*)(s + i);
  d[i + 0] = __float2bfloat16(v.x);
  d[i + 1] = __float2bfloat16(v.y);
  d[i + 2] = __float2bfloat16(v.z);
  d[i + 3] = __float2bfloat16(v.w);
}

// ---------------- GroupNorm (f32 in) -> transposed (N, C) bf16 -----------
__global__ __launch_bounds__(256) void gnorm_kernel(
    const float* __restrict__ xy,
    const float* __restrict__ nw,
    const float* __restrict__ nb,
    bf16_t* __restrict__ hn_t,
    bf16_t* __restrict__ yn_t)
{
  const int bx    = blockIdx.x;      // 256 blocks = 8 b * 2 which * 16 g
  const int b     = bx >> 5;
  const int rest  = bx & 31;
  const int which = rest >> 4;
  const int g     = rest & 15;

  const float* src = xy + (((long)b * 512 + which * 256 + g * 16) << 12);
  bf16_t* dst = (which ? yn_t : hn_t) + ((long)b << 20) + g * 16;

  const int tid = threadIdx.x;

  float sum = 0.f, ss = 0.f;
  const float4* src4 = (const float4*)src;
  for (int i = tid; i < 16384; i += 256) {
    float4 v = src4[i];
    sum += (v.x + v.y) + (v.z + v.w);
    ss = fmaf(v.x, v.x, ss); ss = fmaf(v.y, v.y, ss);
    ss = fmaf(v.z, v.z, ss); ss = fmaf(v.w, v.w, ss);
  }
  #pragma unroll
  for (int off = 32; off > 0; off >>= 1) {
    sum += __shfl_down(sum, off);
    ss  += __shfl_down(ss, off);
  }
  __shared__ float rbuf[8];
  const int w = tid >> 6, lane = tid & 63;
  if (lane == 0) { rbuf[w] = sum; rbuf[4 + w] = ss; }
  __syncthreads();
  const float inv = 1.f / 65536.f;
  const float mu  = (rbuf[0] + rbuf[1] + rbuf[2] + rbuf[3]) * inv;
  const float var = (rbuf[4] + rbuf[5] + rbuf[6] + rbuf[7]) * inv - mu * mu;
  const float rs  = rsqrtf(var + 1e-6f);

  const int   cl = tid & 15;
  const float a  = nw[g * 16 + cl] * rs;
  const float c  = nb[g * 16 + cl] - mu * a;
  const float* srow = src + ((long)cl << 12);
  for (int n = tid >> 4; n < 4096; n += 16) {
    dst[((long)n << 8) + cl] = __float2bfloat16(fmaf(srow[n], a, c));
  }
}

// ---------------- NT GEMM: C[m][n] = sum_k A[m][k] * B[n][k]  (K = 256) ---
template <bool F32OUT>
__global__ __launch_bounds__(256) void gemm_nt_kernel(
    const bf16_t* __restrict__ A,  long sA,
    const bf16_t* __restrict__ Bm, long sB,
    void* __restrict__ Co_,        long sC,
    int Nn,
    const float* __restrict__ bias, int bias_row,
    const float* __restrict__ resid, long sR)
{
  const int b = blockIdx.z;
  A  += (long)b * sA;
  Bm += (long)b * sB;

  const int tid  = threadIdx.x;
  const int w    = tid >> 6, lane = tid & 63;
  const int rowq = lane & 15, kg = lane >> 4;
  const int m0   = blockIdx.x * 64 + w * 16;
  const int n0   = blockIdx.y * 64;

  f32x4 acc[4] = {};
  const bf16x8* arow = (const bf16x8*)(A + (long)(m0 + rowq) * 256 + kg * 8);
  #pragma unroll
  for (int kc = 0; kc < 8; ++kc) {
    bf16x8 af = arow[kc * 4];
    #pragma unroll
    for (int nt = 0; nt < 4; ++nt) {
      bf16x8 bfr = *(const bf16x8*)(Bm + (long)(n0 + nt * 16 + rowq) * 256 + kc * 32 + kg * 8);
      acc[nt] = MFMA(af, bfr, acc[nt]);
    }
  }
  const int r0 = kg * 4;
  #pragma unroll
  for (int nt = 0; nt < 4; ++nt) {
    #pragma unroll
    for (int r = 0; r < 4; ++r) {
      const int row = m0 + r0 + r;
      const int col = n0 + nt * 16 + rowq;
      float vv = acc[nt][r] + bias[bias_row ? row : col];
      if (resid) vv += resid[(long)b * sR + (long)row * Nn + col];
      const long ci = (long)b * sC + (long)row * Nn + col;
      if (F32OUT) ((float*)Co_)[ci] = vv;
      else        ((bf16_t*)Co_)[ci] = __float2bfloat16(vv);
    }
  }
}

// ---------------- Flash attention: O = softmax(Q K^T / 16) V ---------------
// grid (32, 8); 4 waves x 32 q-rows = 128 q-rows per block; 1 wave/SIMD.
// Swapped QK^T (S^T = mfma(K, Q)): lane owns q = qt*16 + (lane&15); softmax
// reduce = 2x shfl_xor. K staged in LDS (dbuf, XOR-swizzled); V read from
// global (L1/L2-resident tile); P through per-wave LDS slice.
__global__ __launch_bounds__(256, 1) void attn_kernel(
    const bf16_t* __restrict__ Q,   // (B, N, C)
    const bf16_t* __restrict__ Kt,  // (B, N, C)
    const bf16_t* __restrict__ V,   // (B, C, N)
    bf16_t* __restrict__ Ht)        // (B, N, C)
{
  __shared__ bf16_t k_lds[2][64 * 256];   // 32KB/buf; row = kv (512B, 32 chunks)
  __shared__ bf16_t p_lds[4][32][72];     // per-wave P: rows=q-local, cols=kv

  const int b  = blockIdx.y;
  const long bo = (long)b << 20;
  const bf16_t* q_t = Q  + bo;
  const bf16_t* k_t = Kt + bo;
  const bf16_t* vb  = V  + bo;
  bf16_t*       h_t = Ht + bo;

  const int tid  = threadIdx.x;
  const int w    = tid >> 6, lane = tid & 63;
  const int rowq = lane & 15, kg = lane >> 4;
  const int q0   = blockIdx.x * 128 + w * 32;

  // K staging (swizzle-inverse pre-applied on global source; LDS dest linear)
  const bf16_t* ksrc[8];
  int koff[8];
  #pragma unroll
  for (int it = 0; it < 8; ++it) {
    const int cl = it * 256 + tid;          // chunk-linear 0..2047
    const int r  = cl >> 5, j = cl & 31;    // 64 rows x 32 chunks of 16B
    ksrc[it] = k_t + r * 256 + ((j ^ (r & 7)) << 3);
    koff[it] = cl << 3;
  }

  // Q fragments (B-operand): lane holds Q[q = q0+qt*16+rowq][kc*32+kg*8 ..+8]
  bf16x8 qf[2][8];
  #pragma unroll
  for (int qt = 0; qt < 2; ++qt)
    #pragma unroll
    for (int kc = 0; kc < 8; ++kc)
      qf[qt][kc] = *(const bf16x8*)(q_t + (long)(q0 + qt * 16 + rowq) * 256 + kc * 32 + kg * 8);

  f32x4 o[2][16] = {};                    // O^T[c = ct*16+4kg+r][q]
  float m2[2] = { -1e30f, -1e30f };       // running max, log2 domain
  float l[2]  = { 0.f, 0.f };
  const float SC2 = 0.0625f * 1.44269504f;

  #pragma unroll
  for (int it = 0; it < 8; ++it) GLOAD_LDS(ksrc[it], &k_lds[0][koff[it]]);

  int cur = 0;
  for (int t = 0; t < 64; ++t) {
    const int kv0 = t << 6;
    __syncthreads();                      // K buf staged; prior reads done
    if (t < 63) {
      #pragma unroll
      for (int it = 0; it < 8; ++it)
        GLOAD_LDS(ksrc[it] + (long)(kv0 + 64) * 256, &k_lds[cur ^ 1][koff[it]]);
    }

    // S^T tiles: s[qt][nt] holds S^T[kv = nt*16+4kg+r][q = qt*16+rowq]
    f32x4 s[2][4] = {};
    #pragma unroll
    for (int nt = 0; nt < 4; ++nt) {
      const int rr = nt * 16 + rowq;
      #pragma unroll
      for (int kc = 0; kc < 8; ++kc) {
        bf16x8 kf = *(const bf16x8*)(
            &k_lds[cur][rr * 256 + (((kc * 4 + kg) ^ (rr & 7)) << 3)]);
        s[0][nt] = MFMA(kf, qf[0][kc], s[0][nt]);
        s[1][nt] = MFMA(kf, qf[1][kc], s[1][nt]);
      }
    }

    // prefetch V kh=0 (global, L1/L2-resident; A-operand rows = c)
    bf16x8 vf0[16];
    #pragma unroll
    for (int ct = 0; ct < 16; ++ct)
      vf0[ct] = *(const bf16x8*)(vb + (long)(ct * 16 + rowq) * 4096 + kv0 + kg * 8);

    // online softmax in log2 domain; per-lane scalar state (q fixed per lane)
    float sv[2][16], rmax[2];
    #pragma unroll
    for (int qt = 0; qt < 2; ++qt) {
      #pragma unroll
      for (int nt = 0; nt < 4; ++nt)
        #pragma unroll
        for (int r = 0; r < 4; ++r) sv[qt][nt * 4 + r] = s[qt][nt][r] * SC2;
      float mx = sv[qt][0];
      #pragma unroll
      for (int i = 1; i < 16; ++i) mx = fmaxf(mx, sv[qt][i]);
      mx = fmaxf(mx, __shfl_xor(mx, 16));
      mx = fmaxf(mx, __shfl_xor(mx, 32));
      rmax[qt] = mx;
    }
    const bool need = (rmax[0] > m2[0] + 11.5f) || (rmax[1] > m2[1] + 11.5f);
    if (__any(need)) {                    // defer-max: rescale only on growth
      #pragma unroll
      for (int qt = 0; qt < 2; ++qt) {
        const float mn = fmaxf(m2[qt], rmax[qt]);
        const float al = exp2f(m2[qt] - mn);
        m2[qt] = mn;
        l[qt] *= al;
        #pragma unroll
        for (int ct = 0; ct < 16; ++ct)
          #pragma unroll
          for (int r = 0; r < 4; ++r) o[qt][ct][r] *= al;
      }
    }
    float p[2][16];
    #pragma unroll
    for (int qt = 0; qt < 2; ++qt) {
      float sm = 0.f;
      #pragma unroll
      for (int i = 0; i < 16; ++i) {
        p[qt][i] = exp2f(sv[qt][i] - m2[qt]);
        sm += p[qt][i];
      }
      sm += __shfl_xor(sm, 16);
      sm += __shfl_xor(sm, 32);
      l[qt] += sm;
    }

    // P -> per-wave p_lds (packed b32 writes); kv-local col = nt*16+4kg+2rp
    #pragma unroll
    for (int qt = 0; qt < 2; ++qt)
      #pragma unroll
      for (int nt = 0; nt < 4; ++nt)
        #pragma unroll
        for (int rp = 0; rp < 2; ++rp) {
          unsigned pkv = pk_bf16(p[qt][nt * 4 + rp * 2], p[qt][nt * 4 + rp * 2 + 1]);
          *(unsigned*)(&p_lds[w][qt * 16 + rowq][nt * 16 + kg * 4 + rp * 2]) = pkv;
        }
    asm volatile("s_waitcnt lgkmcnt(0)" ::: "memory");
    __builtin_amdgcn_sched_barrier(0);

    // O^T += V . P  (A = V rows from global, B = P rows from p_lds)
    bf16x8 pf0[2], pf1[2];
    #pragma unroll
    for (int qt = 0; qt < 2; ++qt)
      pf0[qt] = *(const bf16x8*)(&p_lds[w][qt * 16 + rowq][kg * 8]);
    bf16x8 vf1[16];
    #pragma unroll
    for (int ct = 0; ct < 16; ++ct)
      vf1[ct] = *(const bf16x8*)(vb + (long)(ct * 16 + rowq) * 4096 + kv0 + 32 + kg * 8);
    #pragma unroll
    for (int ct = 0; ct < 16; ++ct) {
      o[0][ct] = MFMA(vf0[ct], pf0[0], o[0][ct]);
      o[1][ct] = MFMA(vf0[ct], pf0[1], o[1][ct]);
    }
    #pragma unroll
    for (int qt = 0; qt < 2; ++qt)
      pf1[qt] = *(const bf16x8*)(&p_lds[w][qt * 16 + rowq][32 + kg * 8]);
    #pragma unroll
    for (int ct = 0; ct < 16; ++ct) {
      o[0][ct] = MFMA(vf1[ct], pf1[0], o[0][ct]);
      o[1][ct] = MFMA(vf1[ct], pf1[1], o[1][ct]);
    }
    cur ^= 1;
  }

  // epilogue: normalize, pack, store O^T -> h_t (N, C)
  #pragma unroll
  for (int qt = 0; qt < 2; ++qt) {
    const float il = 1.f / l[qt];
    bf16_t* hrow = h_t + (long)(q0 + qt * 16 + rowq) * 256;
    #pragma unroll
    for (int ct = 0; ct < 16; ++ct) {
      unsigned u0 = pk_bf16(o[qt][ct][0] * il, o[qt][ct][1] * il);
      unsigned u1 = pk_bf16(o[qt][ct][2] * il, o[qt][ct][3] * il);
      uint2 uu = make_uint2(u0, u1);
      *(uint2*)(hrow + ct * 16 + kg * 4) = uu;
    }
  }
}

extern "C" void kernel_launch(void* const* d_in, const int* in_sizes, int n_in,
                              void* d_out, int out_size, void* d_ws, size_t ws_size,
                              hipStream_t stream)
{
  const float* xy  = (const float*)d_in[0];
  const float* nw  = (const float*)d_in[1];
  const float* nb  = (const float*)d_in[2];
  const float* q_w = (const float*)d_in[3];
  const float* q_b = (const float*)d_in[4];
  const float* k_w = (const float*)d_in[5];
  const float* k_b = (const float*)d_in[6];
  const float* v_w = (const float*)d_in[7];
  const float* v_b = (const float*)d_in[8];
  const float* p_w = (const float*)d_in[9];
  const float* p_b = (const float*)d_in[10];
  float*  out = (float*)d_out;
  bf16_t* ws  = (bf16_t*)d_ws;

  const long SZ = (long)8 * 4096 * 256;
  bf16_t* wq   = ws;
  bf16_t* wk   = ws + 65536;
  bf16_t* wv   = ws + 131072;
  bf16_t* wp   = ws + 196608;
  bf16_t* hn_t = ws + 262144;
  bf16_t* yn_t = hn_t + SZ;
  bf16_t* q_t  = hn_t + 2 * SZ;
  bf16_t* k_t  = hn_t + 3 * SZ;
  bf16_t* vbuf = hn_t + 4 * SZ;
  bf16_t* h_t  = yn_t;                    // yn dead after q GEMM

  const long nc = (long)4096 * 256;

  cvtw_kernel<<<dim3(64, 4), 256, 0, stream>>>(q_w, k_w, v_w, p_w, wq);

  gnorm_kernel<<<256, 256, 0, stream>>>(xy, nw, nb, hn_t, yn_t);

  gemm_nt_kernel<false><<<dim3(64, 4, 8), 256, 0, stream>>>(
      yn_t, nc, wq, 0, q_t, nc, 256, q_b, 0, nullptr, 0);
  gemm_nt_kernel<false><<<dim3(64, 4, 8), 256, 0, stream>>>(
      hn_t, nc, wk, 0, k_t, nc, 256, k_b, 0, nullptr, 0);
  gemm_nt_kernel<false><<<dim3(4, 64, 8), 256, 0, stream>>>(
      wv, 0, hn_t, nc, vbuf, nc, 4096, v_b, 1, nullptr, 0);

  attn_kernel<<<dim3(32, 8), 256, 0, stream>>>(q_t, k_t, vbuf, h_t);

  gemm_nt_kernel<true><<<dim3(4, 64, 8), 256, 0, stream>>>(
      wp, 0, h_t, nc, out, nc, 4096, p_b, 1, xy, (long)512 * 4096);
}

// Round 7
// 444.630 us; speedup vs baseline: 1.5423x; 1.5423x over previous
//
#include <hip/hip_runtime.h>
#include <hip/hip_bf16.h>

using bf16_t  = __hip_bfloat16;
using bf16x8  = __attribute__((ext_vector_type(8))) __bf16;
using f32x4   = __attribute__((ext_vector_type(4))) float;
using f32x16  = __attribute__((ext_vector_type(16))) float;
using u32x2   = __attribute__((ext_vector_type(2))) unsigned;

#define MFMA(a, b, c)   __builtin_amdgcn_mfma_f32_16x16x32_bf16((a), (b), (c), 0, 0, 0)
#define MFMA32(a, b, c) __builtin_amdgcn_mfma_f32_32x32x16_bf16((a), (b), (c), 0, 0, 0)

#define GLOAD_LDS(g, l) __builtin_amdgcn_global_load_lds(                      \
    (const __attribute__((address_space(1))) void*)(g),                        \
    (__attribute__((address_space(3))) void*)(l), 16, 0, 0)

static __device__ __forceinline__ unsigned pk_bf16(float lo, float hi) {
  unsigned r;
  asm volatile("v_cvt_pk_bf16_f32 %0, %1, %2" : "=v"(r) : "v"(lo), "v"(hi));
  return r;
}

static __device__ __forceinline__ void lane32_swap(unsigned& a, unsigned& b) {
#if __has_builtin(__builtin_amdgcn_permlane32_swap)
  u32x2 r = __builtin_amdgcn_permlane32_swap(a, b, false, false);
  a = r[0]; b = r[1];
#else
  asm volatile("v_permlane32_swap_b32 %0, %1" : "+v"(a), "+v"(b));
#endif
}

// B=8, C=256, N=4096(=64x64), 16 groups of 16 channels. f32 I/O, bf16 internal.

// -------- convert 4 weight matrices (256x256 f32) to bf16 ----------------
__global__ __launch_bounds__(256) void cvtw_kernel(
    const float* __restrict__ w0, const float* __restrict__ w1,
    const float* __restrict__ w2, const float* __restrict__ w3,
    bf16_t* __restrict__ dst)
{
  const float* s;
  switch (blockIdx.y) {
    case 0: s = w0; break;
    case 1: s = w1; break;
    case 2: s = w2; break;
    default: s = w3; break;
  }
  bf16_t* d = dst + (long)blockIdx.y * 65536;
  const int i = (blockIdx.x * 256 + threadIdx.x) * 4;
  float4 v = *(const float4*)(s + i);
  d[i + 0] = __float2bfloat16(v.x);
  d[i + 1] = __float2bfloat16(v.y);
  d[i + 2] = __float2bfloat16(v.z);
  d[i + 3] = __float2bfloat16(v.w);
}

// ---------------- GroupNorm (f32 in) -> transposed (N, C) bf16 -----------
__global__ __launch_bounds__(256) void gnorm_kernel(
    const float* __restrict__ xy,
    const float* __restrict__ nw,
    const float* __restrict__ nb,
    bf16_t* __restrict__ hn_t,
    bf16_t* __restrict__ yn_t)
{
  const int bx    = blockIdx.x;
  const int b     = bx >> 5;
  const int rest  = bx & 31;
  const int which = rest >> 4;
  const int g     = rest & 15;

  const float* src = xy + (((long)b * 512 + which * 256 + g * 16) << 12);
  bf16_t* dst = (which ? yn_t : hn_t) + ((long)b << 20) + g * 16;

  const int tid = threadIdx.x;

  float sum = 0.f, ss = 0.f;
  const float4* src4 = (const float4*)src;
  for (int i = tid; i < 16384; i += 256) {
    float4 v = src4[i];
    sum += (v.x + v.y) + (v.z + v.w);
    ss = fmaf(v.x, v.x, ss); ss = fmaf(v.y, v.y, ss);
    ss = fmaf(v.z, v.z, ss); ss = fmaf(v.w, v.w, ss);
  }
  #pragma unroll
  for (int off = 32; off > 0; off >>= 1) {
    sum += __shfl_down(sum, off);
    ss  += __shfl_down(ss, off);
  }
  __shared__ float rbuf[8];
  const int w = tid >> 6, lane = tid & 63;
  if (lane == 0) { rbuf[w] = sum; rbuf[4 + w] = ss; }
  __syncthreads();
  const float inv = 1.f / 65536.f;
  const float mu  = (rbuf[0] + rbuf[1] + rbuf[2] + rbuf[3]) * inv;
  const float var = (rbuf[4] + rbuf[5] + rbuf[6] + rbuf[7]) * inv - mu * mu;
  const float rs  = rsqrtf(var + 1e-6f);

  const int   cl = tid & 15;
  const float a  = nw[g * 16 + cl] * rs;
  const float c  = nb[g * 16 + cl] - mu * a;
  const float* srow = src + ((long)cl << 12);
  for (int n = tid >> 4; n < 4096; n += 16) {
    dst[((long)n << 8) + cl] = __float2bfloat16(fmaf(srow[n], a, c));
  }
}

// ---------------- NT GEMM: C[m][n] = sum_k A[m][k] * B[n][k]  (K = 256) ---
template <bool F32OUT>
__global__ __launch_bounds__(256) void gemm_nt_kernel(
    const bf16_t* __restrict__ A,  long sA,
    const bf16_t* __restrict__ Bm, long sB,
    void* __restrict__ Co_,        long sC,
    int Nn,
    const float* __restrict__ bias, int bias_row,
    const float* __restrict__ resid, long sR)
{
  const int b = blockIdx.z;
  A  += (long)b * sA;
  Bm += (long)b * sB;

  const int tid  = threadIdx.x;
  const int w    = tid >> 6, lane = tid & 63;
  const int rowq = lane & 15, kg = lane >> 4;
  const int m0   = blockIdx.x * 64 + w * 16;
  const int n0   = blockIdx.y * 64;

  f32x4 acc[4] = {};
  const bf16x8* arow = (const bf16x8*)(A + (long)(m0 + rowq) * 256 + kg * 8);
  #pragma unroll
  for (int kc = 0; kc < 8; ++kc) {
    bf16x8 af = arow[kc * 4];
    #pragma unroll
    for (int nt = 0; nt < 4; ++nt) {
      bf16x8 bfr = *(const bf16x8*)(Bm + (long)(n0 + nt * 16 + rowq) * 256 + kc * 32 + kg * 8);
      acc[nt] = MFMA(af, bfr, acc[nt]);
    }
  }
  const int r0 = kg * 4;
  #pragma unroll
  for (int nt = 0; nt < 4; ++nt) {
    #pragma unroll
    for (int r = 0; r < 4; ++r) {
      const int row = m0 + r0 + r;
      const int col = n0 + nt * 16 + rowq;
      float vv = acc[nt][r] + bias[bias_row ? row : col];
      if (resid) vv += resid[(long)b * sR + (long)row * Nn + col];
      const long ci = (long)b * sC + (long)row * Nn + col;
      if (F32OUT) ((float*)Co_)[ci] = vv;
      else        ((bf16_t*)Co_)[ci] = __float2bfloat16(vv);
    }
  }
}

// ---------------- Flash attention: O = softmax(Q K^T / 16) V ---------------
// grid (32, 8); 4 waves x 32 q-rows (Mw=32, 32x32x16 MFMA); KVBLK=64.
// K (kv,C) and V (C,kv) double-buffered in LDS (128 KB), XOR-swizzled both
// sides. Swapped QK^T -> S^T[kv][q=lane&31]; P assembled in-register via
// cvt_pk + permlane32_swap (no P LDS). 1 block/CU; DS pipe fed by 4 waves.
__global__ __launch_bounds__(256, 1) void attn_kernel(
    const bf16_t* __restrict__ Q,   // (B, N, C)
    const bf16_t* __restrict__ Kt,  // (B, N, C)
    const bf16_t* __restrict__ V,   // (B, C, N)
    bf16_t* __restrict__ Ht)        // (B, N, C)
{
  __shared__ bf16_t k_lds[2][64 * 256];   // 32KB/buf; row=kv, 512B (32 chunks)
  __shared__ bf16_t v_lds[2][256 * 64];   // 32KB/buf; row=c,  128B (8 chunks)

  const int b  = blockIdx.y;
  const long bo = (long)b << 20;
  const bf16_t* q_t = Q  + bo;
  const bf16_t* k_t = Kt + bo;
  const bf16_t* vb  = V  + bo;
  bf16_t*       h_t = Ht + bo;

  const int tid  = threadIdx.x;
  const int w    = tid >> 6, lane = tid & 63;
  const int ql   = lane & 31, hi = lane >> 5;
  const int q0   = blockIdx.x * 128 + w * 32;

  // staging offsets (global elems), swizzle-inverse pre-applied; LDS linear.
  int kgoff[8], vgoff[8];
  #pragma unroll
  for (int it = 0; it < 8; ++it) {
    const int cl = it * 256 + tid;          // 2048 chunks of 16B
    const int r  = cl >> 5, j = cl & 31;    // K: 64 rows x 32 chunks
    kgoff[it] = r * 256 + ((j ^ (r & 7)) << 3);
    const int c = cl >> 3, jv = cl & 7;     // V: 256 rows x 8 chunks
    vgoff[it] = c * 4096 + ((jv ^ (c & 7)) << 3);
  }

  // Q fragments (B-operand): lane holds Q[q0+ql][cs*16 + hi*8 .. +8]
  bf16x8 qf[16];
  #pragma unroll
  for (int cs = 0; cs < 16; ++cs)
    qf[cs] = *(const bf16x8*)(q_t + (long)(q0 + ql) * 256 + cs * 16 + hi * 8);

  f32x16 o[8] = {};            // O^T[c = cb*32 + (reg&3)+8*(reg>>2)+4*hi][q=ql]
  float m2 = -1e30f, lsum = 0.f;
  const float SC2 = 0.0625f * 1.44269504f;   // scale * log2(e)

  // prologue: stage tile 0 into buf 0
  #pragma unroll
  for (int it = 0; it < 8; ++it)
    GLOAD_LDS(k_t + kgoff[it], &k_lds[0][(it * 256 + tid) * 8]);
  #pragma unroll
  for (int it = 0; it < 8; ++it)
    GLOAD_LDS(vb + vgoff[it], &v_lds[0][(it * 256 + tid) * 8]);

  int cur = 0;
  for (int t = 0; t < 64; ++t) {
    const int kv0 = t << 6;
    __syncthreads();                        // buf[cur] staged; prior reads done
    if (t < 63) {
      #pragma unroll
      for (int it = 0; it < 8; ++it)
        GLOAD_LDS(k_t + (long)(kv0 + 64) * 256 + kgoff[it],
                  &k_lds[cur ^ 1][(it * 256 + tid) * 8]);
      #pragma unroll
      for (int it = 0; it < 8; ++it)
        GLOAD_LDS(vb + (kv0 + 64) + vgoff[it],
                  &v_lds[cur ^ 1][(it * 256 + tid) * 8]);
    }

    // S^T = K . Q^T : two 32x32 tiles (kv halves), K from LDS
    f32x16 s0 = {}, s1 = {};
    #pragma unroll
    for (int cs = 0; cs < 16; ++cs) {
      const int g = cs * 2 + hi;
      const int sw = (g ^ (ql & 7)) << 3;
      bf16x8 kf0 = *(const bf16x8*)(&k_lds[cur][ql * 256 + sw]);
      bf16x8 kf1 = *(const bf16x8*)(&k_lds[cur][(32 + ql) * 256 + sw]);
      s0 = MFMA32(kf0, qf[cs], s0);
      s1 = MFMA32(kf1, qf[cs], s1);
    }

    // online softmax (log2 domain); lane owns q=ql, kv rows lane-local
    float p0[16], p1[16];
    #pragma unroll
    for (int i = 0; i < 16; ++i) { p0[i] = s0[i] * SC2; p1[i] = s1[i] * SC2; }
    float mx = p0[0];
    #pragma unroll
    for (int i = 1; i < 16; ++i) mx = fmaxf(mx, p0[i]);
    #pragma unroll
    for (int i = 0; i < 16; ++i) mx = fmaxf(mx, p1[i]);
    mx = fmaxf(mx, __shfl_xor(mx, 32));
    if (__any(mx > m2 + 11.5f)) {           // defer-max rescale
      const float mn = fmaxf(m2, mx);
      const float al = exp2f(m2 - mn);
      m2 = mn;
      lsum *= al;
      #pragma unroll
      for (int cb = 0; cb < 8; ++cb)
        #pragma unroll
        for (int i = 0; i < 16; ++i) o[cb][i] *= al;
    }
    float sm = 0.f;
    #pragma unroll
    for (int i = 0; i < 16; ++i) {
      p0[i] = exp2f(p0[i] - m2); sm += p0[i];
      p1[i] = exp2f(p1[i] - m2); sm += p1[i];
    }
    lsum += sm;                             // per-lane partial; merge at end

    // P^T B-operand assembly: cvt_pk pairs + permlane32_swap (no LDS)
    bf16x8 pb[4];
    {
      unsigned wd[8];
      #pragma unroll
      for (int j = 0; j < 8; ++j) wd[j] = pk_bf16(p0[2 * j], p0[2 * j + 1]);
      lane32_swap(wd[0], wd[2]); lane32_swap(wd[1], wd[3]);
      lane32_swap(wd[4], wd[6]); lane32_swap(wd[5], wd[7]);
      union { unsigned u[4]; bf16x8 v; } a0, a1;
      a0.u[0] = wd[0]; a0.u[1] = wd[1]; a0.u[2] = wd[2]; a0.u[3] = wd[3];
      a1.u[0] = wd[4]; a1.u[1] = wd[5]; a1.u[2] = wd[6]; a1.u[3] = wd[7];
      pb[0] = a0.v; pb[1] = a1.v;
      #pragma unroll
      for (int j = 0; j < 8; ++j) wd[j] = pk_bf16(p1[2 * j], p1[2 * j + 1]);
      lane32_swap(wd[0], wd[2]); lane32_swap(wd[1], wd[3]);
      lane32_swap(wd[4], wd[6]); lane32_swap(wd[5], wd[7]);
      a0.u[0] = wd[0]; a0.u[1] = wd[1]; a0.u[2] = wd[2]; a0.u[3] = wd[3];
      a1.u[0] = wd[4]; a1.u[1] = wd[5]; a1.u[2] = wd[6]; a1.u[3] = wd[7];
      pb[2] = a0.v; pb[3] = a1.v;
    }

    // O^T += V . P^T, V from LDS
    #pragma unroll
    for (int ks = 0; ks < 4; ++ks) {
      const int g = ks * 2 + hi;
      #pragma unroll
      for (int cb = 0; cb < 8; ++cb) {
        const int c = cb * 32 + ql;
        bf16x8 vf = *(const bf16x8*)(&v_lds[cur][c * 64 + ((g ^ (c & 7)) << 3)]);
        o[cb] = MFMA32(vf, pb[ks], o[cb]);
      }
    }
    cur ^= 1;
  }

  // epilogue: merge l across lane pair, normalize, pack, store (N,C)
  lsum += __shfl_xor(lsum, 32);
  const float il = 1.f / lsum;
  bf16_t* hrow = h_t + (long)(q0 + ql) * 256;
  #pragma unroll
  for (int cb = 0; cb < 8; ++cb) {
    #pragma unroll
    for (int pg = 0; pg < 4; ++pg) {
      unsigned u0 = pk_bf16(o[cb][pg * 4 + 0] * il, o[cb][pg * 4 + 1] * il);
      unsigned u1 = pk_bf16(o[cb][pg * 4 + 2] * il, o[cb][pg * 4 + 3] * il);
      uint2 uu = make_uint2(u0, u1);
      *(uint2*)(hrow + cb * 32 + pg * 8 + hi * 4) = uu;
    }
  }
}

extern "C" void kernel_launch(void* const* d_in, const int* in_sizes, int n_in,
                              void* d_out, int out_size, void* d_ws, size_t ws_size,
                              hipStream_t stream)
{
  const float* xy  = (const float*)d_in[0];
  const float* nw  = (const float*)d_in[1];
  const float* nb  = (const float*)d_in[2];
  const float* q_w = (const float*)d_in[3];
  const float* q_b = (const float*)d_in[4];
  const float* k_w = (const float*)d_in[5];
  const float* k_b = (const float*)d_in[6];
  const float* v_w = (const float*)d_in[7];
  const float* v_b = (const float*)d_in[8];
  const float* p_w = (const float*)d_in[9];
  const float* p_b = (const float*)d_in[10];
  float*  out = (float*)d_out;
  bf16_t* ws  = (bf16_t*)d_ws;

  const long SZ = (long)8 * 4096 * 256;
  bf16_t* wq   = ws;
  bf16_t* wk   = ws + 65536;
  bf16_t* wv   = ws + 131072;
  bf16_t* wp   = ws + 196608;
  bf16_t* hn_t = ws + 262144;
  bf16_t* yn_t = hn_t + SZ;
  bf16_t* q_t  = hn_t + 2 * SZ;
  bf16_t* k_t  = hn_t + 3 * SZ;
  bf16_t* vbuf = hn_t + 4 * SZ;
  bf16_t* h_t  = yn_t;                    // yn dead after q GEMM

  const long nc = (long)4096 * 256;

  cvtw_kernel<<<dim3(64, 4), 256, 0, stream>>>(q_w, k_w, v_w, p_w, wq);

  gnorm_kernel<<<256, 256, 0, stream>>>(xy, nw, nb, hn_t, yn_t);

  gemm_nt_kernel<false><<<dim3(64, 4, 8), 256, 0, stream>>>(
      yn_t, nc, wq, 0, q_t, nc, 256, q_b, 0, nullptr, 0);
  gemm_nt_kernel<false><<<dim3(64, 4, 8), 256, 0, stream>>>(
      hn_t, nc, wk, 0, k_t, nc, 256, k_b, 0, nullptr, 0);
  gemm_nt_kernel<false><<<dim3(4, 64, 8), 256, 0, stream>>>(
      wv, 0, hn_t, nc, vbuf, nc, 4096, v_b, 1, nullptr, 0);

  attn_kernel<<<dim3(32, 8), 256, 0, stream>>>(q_t, k_t, vbuf, h_t);

  gemm_nt_kernel<true><<<dim3(4, 64, 8), 256, 0, stream>>>(
      wp, 0, h_t, nc, out, nc, 4096, p_b, 1, xy, (long)512 * 4096);
}